// Round 9
// baseline (129.022 us; speedup 1.0000x reference)
//
#include <hip/hip_runtime.h>
#include <hip/hip_bf16.h>

typedef unsigned short u16;
typedef unsigned long long u64;
typedef __attribute__((ext_vector_type(8))) short short8;
typedef __attribute__((ext_vector_type(4))) float f32x4;

#define TMAX 200
#define TOUT 198
#define PC 40
#define DOTH 57
#define FWD_OFF 0
#define BWD_OFF 3244032
#define FV_OFF  6488064
// ws byte offsets: packed bf16 weights + f32 tgt folds
#define OWF 0
#define OWB 294912
#define OW0 589824
#define OW1 884736
#define OTF 1015808
#define OTB 1081344

__device__ __forceinline__ u16 f2b(float v) {
  __hip_bfloat16 h = __float2bfloat16(v);
  return *(u16*)&h;
}

// bits (8) -> bf16 one-hot fragment
__device__ __forceinline__ short8 expand8(unsigned byte) {
  short8 v;
  #pragma unroll
  for (int j = 0; j < 8; j++) v[j] = ((byte >> j) & 1u) ? (short)0x3F80 : (short)0;
  return v;
}

// Pack weights to MFMA-frag layout + fold per-batch target block.
// Packed K order (mode 0, Wf/Wb): k 0..56 = dense (orig rows 607+k),
// k 57..563 = code one-hots (orig rows k-57), rest 0.
// mode 1 (W0): k 0..47 = dense (orig 507+k), 48..56 = 0, 57..563 = codes.
__global__ __launch_bounds__(256) void prep_kernel(
    const int* __restrict__ target, const int* __restrict__ widx,
    const float* __restrict__ Wf, const float* __restrict__ bfv,
    const float* __restrict__ Wb, const float* __restrict__ bbv,
    const float* __restrict__ W0, const float* __restrict__ W1,
    u16* __restrict__ wsu, float* __restrict__ wsf)
{
  int blk = blockIdx.x, n = threadIdx.x;
  if (blk < 248) {
    const float* src; u16* dst; int kb; int mode;
    if (blk < 72)       { src=Wf; dst=wsu+OWF/2; kb=blk;     mode=0; }
    else if (blk < 144) { src=Wb; dst=wsu+OWB/2; kb=blk-72;  mode=0; }
    else if (blk < 216) { src=W0; dst=wsu+OW0/2; kb=blk-144; mode=1; }
    else                { src=W1; dst=wsu+OW1/2; kb=blk-216; mode=2; }
    u16 pk[8];
    #pragma unroll
    for (int j=0;j<8;j++) {
      int k = kb*8+j;
      int sr;
      if (mode==0)      sr = (k<57)? 607+k : (k<564)? k-57 : -1;
      else if (mode==1) sr = (k<48)? 507+k : (k<57)? -1 : (k<564)? k-57 : -1;
      else              sr = k;
      float v = (sr>=0)? src[sr*256+n] : 0.f;
      pk[j] = f2b(v);
    }
    *(uint4*)(dst + (kb*256+n)*8) = *(uint4*)pk;
  } else {
    int b = blk - 248;
    __shared__ float tval[100]; __shared__ int tg[10];
    if (n<10) tg[n]=target[b*10+n];
    __syncthreads();
    if (n<100){ int w=widx[n]; float v=1.f;
      #pragma unroll
      for(int i=0;i<10;i++) if(tg[i]==w) v=0.f;
      tval[n]=v; }
    __syncthreads();
    float aF=bfv[n], aB=bbv[n];
    for(int k=0;k<100;k++){ float v=tval[k];
      aF=fmaf(v,Wf[(507+k)*256+n],aF); aB=fmaf(v,Wb[(507+k)*256+n],aB); }
    wsf[OTF/4 + b*256+n]=aF; wsf[OTB/4 + b*256+n]=aB;
  }
}

__global__ __launch_bounds__(256, 4) void gemm_kernel(
    const int* __restrict__ code, const float* __restrict__ others,
    const int* __restrict__ length,
    const float* __restrict__ b0, const float* __restrict__ b1,
    const u16* __restrict__ wsu, const float* __restrict__ wsf,
    float* __restrict__ out)
{
  const int tile = blockIdx.x;   // 0..395 (M-tiles of 32)
  const int strm = blockIdx.y;   // 0 fwd, 1 bwd, 2 mlp
  const int tid = threadIdx.x;
  const int wv = tid>>6, lane = tid&63, q = lane>>4, c = lane&15;
  const int colbase = wv*64 + c;

  __shared__ u16 lA[2048];           // kt0 A-tile (dense dims + codes<7), 4 KB
  __shared__ u16 lH[2][2048];        // GEMM2 h-chunk ping-pong (strm2 only)
  __shared__ unsigned bm[32][18];    // per-row 512-bit occupancy bitmap, padded
  __shared__ float rpart[4][32];

  // ---- code loads (row meta computed inline; no LDS dependency) ----
  int mys[5];
  #pragma unroll
  for (int it=0; it<5; it++) {
    int idx = tid + it*256;
    int r = idx/40, p = idx - r*40;
    int m = tile*32 + r;
    int b = m/198, t = m - b*198;
    int L = length[b];
    int s;
    if (strm==0) s = t;
    else if (strm==1) s = (t<L)? (L-1-t) : t;
    else s = t+1;
    mys[it] = (57 + code[(b*TMAX + s)*PC + p]) | (r<<16);
  }

  // ---- dense-dim loads into registers ----
  float dv[8];
  if (strm < 2) {
    #pragma unroll
    for (int it=0; it<8; it++) {
      int idx = tid + it*256;
      float v = 0.f;
      if (idx < 32*57) {
        int r = idx/57, j = idx - r*57;
        int m = tile*32 + r;
        int b = m/198, t = m - b*198;
        int L = length[b];
        int col = (j<27)? j : (j<47)? 37+(j-27) : 27+(j-47);
        int sr;
        if (strm==0) sr = t;
        else if (j < 47) sr = (t<L)? (L-1-t) : t;
        else sr = (t==0)? -1 : (((t-1)<L)? (L-t) : (t-1));
        if (sr >= 0) v = others[(b*TMAX + sr)*DOTH + col];
      }
      dv[it] = v;
    }
  } else {
    #pragma unroll
    for (int it=0; it<6; it++) {
      int idx = tid + it*256;
      int r = idx/48, j = idx - r*48;
      int m = tile*32 + r;
      int b = m/198, t = m - b*198;
      int srow, col;
      if (j<20)      { srow=t+1; col=37+j; }
      else if (j<30) { srow=t+1; col=27+(j-20); }
      else if (j<40) { srow=t+2; col=27+(j-30); }
      else           { srow=t+1; col=19+(j-40); }
      dv[it] = others[(b*TMAX + srow)*DOTH + col];
    }
  }

  // ---- zero lA + bitmap ----
  { uint4 z = {0,0,0,0}; ((uint4*)lA)[tid] = z; }
  for (int idx = tid; idx < 32*18; idx += 256) ((unsigned*)bm)[idx] = 0u;
  __syncthreads();

  // ---- scatter: codes<7 -> lA window0; codes>=7 -> bitmap ----
  #pragma unroll
  for (int it=0; it<5; it++) {
    unsigned d = (unsigned)(mys[it] & 0xFFFF);
    int r = mys[it] >> 16;
    if (d < 64u) lA[(d>>3)*256 + r*8 + (d&7)] = 0x3F80;
    else {
      unsigned kb = d - 64u;
      atomicOr(&bm[r][kb>>5], 1u << (kb & 31u));
    }
  }
  // dense dims -> lA (k = j)
  if (strm < 2) {
    #pragma unroll
    for (int it=0; it<8; it++) {
      int idx = tid + it*256;
      if (idx < 32*57) {
        int r = idx/57, j = idx - r*57;
        lA[(j>>3)*256 + r*8 + (j&7)] = f2b(dv[it]);
      }
    }
  } else {
    #pragma unroll
    for (int it=0; it<6; it++) {
      int idx = tid + it*256;
      int r = idx/48, j = idx - r*48;
      lA[(j>>3)*256 + r*8 + (j&7)] = f2b(dv[it]);
    }
  }
  __syncthreads();

  // ---- K-loop: kt0 from lA, kt1..8 barrier-free from bitmap ----
  f32x4 acc[2][4];
  #pragma unroll
  for (int mt=0; mt<2; mt++)
    #pragma unroll
    for (int nt=0; nt<4; nt++)
      #pragma unroll
      for (int reg=0; reg<4; reg++) acc[mt][nt][reg] = 0.f;

  const u16* Wpk = wsu + ((strm==0)? OWF/2 : (strm==1)? OWB/2 : OW0/2);
  {
    const u16* gB0 = Wpk + ((q    )*256 + colbase)*8;
    const u16* gB1 = Wpk + ((4 + q)*256 + colbase)*8;
    short8 bf0[4], bf1[4];
    #pragma unroll
    for (int nt=0; nt<4; nt++) bf0[nt] = *(const short8*)(gB0 + nt*16*8);
    #pragma unroll
    for (int nt=0; nt<4; nt++) bf1[nt] = *(const short8*)(gB1 + nt*16*8);
    short8 af0[2], af1[2];
    #pragma unroll
    for (int mt=0; mt<2; mt++) af0[mt] = *(const short8*)&lA[(q    )*256 + (mt*16 + c)*8];
    #pragma unroll
    for (int mt=0; mt<2; mt++) af1[mt] = *(const short8*)&lA[(4 + q)*256 + (mt*16 + c)*8];
    #pragma unroll
    for (int mt=0; mt<2; mt++)
      #pragma unroll
      for (int nt=0; nt<4; nt++)
        acc[mt][nt] = __builtin_amdgcn_mfma_f32_16x16x32_bf16(af0[mt], bf0[nt], acc[mt][nt], 0,0,0);
    #pragma unroll
    for (int mt=0; mt<2; mt++)
      #pragma unroll
      for (int nt=0; nt<4; nt++)
        acc[mt][nt] = __builtin_amdgcn_mfma_f32_16x16x32_bf16(af1[mt], bf1[nt], acc[mt][nt], 0,0,0);
  }
  #pragma unroll
  for (int kt=1; kt<9; kt++) {
    const u16* gB0 = Wpk + ((kt*8 + q    )*256 + colbase)*8;
    const u16* gB1 = Wpk + ((kt*8 + 4 + q)*256 + colbase)*8;
    short8 bf0[4], bf1[4];
    #pragma unroll
    for (int nt=0; nt<4; nt++) bf0[nt] = *(const short8*)(gB0 + nt*16*8);
    #pragma unroll
    for (int nt=0; nt<4; nt++) bf1[nt] = *(const short8*)(gB1 + nt*16*8);
    u64 w0 = *(const u64*)&bm[c][2*(kt-1)];
    u64 w1 = *(const u64*)&bm[16+c][2*(kt-1)];
    unsigned b00 = (unsigned)(w0 >> (q*8))        & 0xFFu;
    unsigned b01 = (unsigned)(w0 >> (32 + q*8))   & 0xFFu;
    unsigned b10 = (unsigned)(w1 >> (q*8))        & 0xFFu;
    unsigned b11 = (unsigned)(w1 >> (32 + q*8))   & 0xFFu;
    short8 a00 = expand8(b00), a01 = expand8(b01);
    short8 a10 = expand8(b10), a11 = expand8(b11);
    #pragma unroll
    for (int nt=0; nt<4; nt++) {
      acc[0][nt] = __builtin_amdgcn_mfma_f32_16x16x32_bf16(a00, bf0[nt], acc[0][nt], 0,0,0);
      acc[1][nt] = __builtin_amdgcn_mfma_f32_16x16x32_bf16(a10, bf0[nt], acc[1][nt], 0,0,0);
    }
    #pragma unroll
    for (int nt=0; nt<4; nt++) {
      acc[0][nt] = __builtin_amdgcn_mfma_f32_16x16x32_bf16(a01, bf1[nt], acc[0][nt], 0,0,0);
      acc[1][nt] = __builtin_amdgcn_mfma_f32_16x16x32_bf16(a11, bf1[nt], acc[1][nt], 0,0,0);
    }
  }

  if (strm < 2) {
    // ---- epilogue: add folded tgt+bias, store ----
    const float* tg = wsf + ((strm==0)? OTF/4 : OTB/4);
    float* o = out + ((strm==0)? FWD_OFF : BWD_OFF);
    #pragma unroll
    for (int mt=0; mt<2; mt++)
      #pragma unroll
      for (int reg=0; reg<4; reg++) {
        int rl = mt*16 + q*4 + reg;
        int m = tile*32 + rl;
        int b = m/198, t = m - b*198;
        const float* tr = tg + b*256;
        float* orow = o + (b*TOUT + t)*256 + colbase;
        #pragma unroll
        for (int nt=0; nt<4; nt++) orow[nt*16] = acc[mt][nt][reg] + tr[colbase + nt*16];
      }
  } else {
    // ---- GEMM2: h = relu(acc + b0); chunks ping-pong via lH; W1 from L2 ----
    if (wv == 0) {
      #pragma unroll
      for (int mt=0; mt<2; mt++)
        #pragma unroll
        for (int reg=0; reg<4; reg++) {
          int rl = mt*16 + q*4 + reg;
          #pragma unroll
          for (int nt=0; nt<4; nt++) {
            int kl = c + nt*16;
            lH[0][(kl>>3)*256 + rl*8 + (kl&7)] =
                f2b(fmaxf(acc[mt][nt][reg] + b0[colbase + nt*16], 0.f));
          }
        }
    }
    __syncthreads();
    f32x4 a2[2][4];
    #pragma unroll
    for (int nt=0; nt<4; nt++){ float v = b1[colbase + nt*16];
      #pragma unroll
      for (int mt=0; mt<2; mt++)
        #pragma unroll
        for (int reg=0; reg<4; reg++) a2[mt][nt][reg]=v; }
    const u16* W1p = wsu + OW1/2;
    for (int kt2=0; kt2<4; kt2++) {
      if (wv == kt2+1) {   // write next chunk into other buffer
        u16* B2 = lH[(kt2+1)&1];
        #pragma unroll
        for (int mt=0; mt<2; mt++)
          #pragma unroll
          for (int reg=0; reg<4; reg++) {
            int rl = mt*16 + q*4 + reg;
            #pragma unroll
            for (int nt=0; nt<4; nt++) {
              int kl = c + nt*16;
              B2[(kl>>3)*256 + rl*8 + (kl&7)] =
                  f2b(fmaxf(acc[mt][nt][reg] + b0[colbase + nt*16], 0.f));
            }
          }
      }
      const u16* A2 = lH[kt2&1];
      #pragma unroll
      for (int s=0; s<2; s++) {
        int akb = s*4 + q;
        const u16* gB = W1p + ((kt2*8 + akb)*256 + colbase)*8;
        short8 af[2], bf[4];
        #pragma unroll
        for (int nt=0; nt<4; nt++) bf[nt] = *(const short8*)(gB + nt*16*8);
        #pragma unroll
        for (int mt=0; mt<2; mt++) af[mt] = *(const short8*)&A2[akb*256 + (mt*16 + c)*8];
        #pragma unroll
        for (int mt=0; mt<2; mt++)
          #pragma unroll
          for (int nt=0; nt<4; nt++)
            a2[mt][nt] = __builtin_amdgcn_mfma_f32_16x16x32_bf16(af[mt], bf[nt], a2[mt][nt], 0,0,0);
      }
      __syncthreads();
    }
    // row-wise sum of squares -> l2norm + mask
    #pragma unroll
    for (int mt=0; mt<2; mt++)
      #pragma unroll
      for (int reg=0; reg<4; reg++) {
        int rl = mt*16 + q*4 + reg;
        float ss = 0.f;
        #pragma unroll
        for (int nt=0; nt<4; nt++){ float v=a2[mt][nt][reg]; ss = fmaf(v,v,ss); }
        ss += __shfl_xor(ss, 1, 64); ss += __shfl_xor(ss, 2, 64);
        ss += __shfl_xor(ss, 4, 64); ss += __shfl_xor(ss, 8, 64);
        if (c==0) rpart[wv][rl] = ss;
      }
    __syncthreads();
    #pragma unroll
    for (int mt=0; mt<2; mt++)
      #pragma unroll
      for (int reg=0; reg<4; reg++) {
        int rl = mt*16 + q*4 + reg;
        float s = rpart[0][rl]+rpart[1][rl]+rpart[2][rl]+rpart[3][rl];
        float inv = (s>0.f)? (1.0f/sqrtf(s)) : 0.f;
        int m = tile*32 + rl;
        int b = m/198, t = m - b*198;
        if (t >= length[b]-2) inv = 0.f;
        float* orow = out + FV_OFF + (b*TOUT + t)*256 + colbase;
        #pragma unroll
        for (int nt=0; nt<4; nt++) orow[nt*16] = a2[mt][nt][reg]*inv;
      }
  }
}

extern "C" void kernel_launch(void* const* d_in, const int* in_sizes, int n_in,
                              void* d_out, int out_size, void* d_ws, size_t ws_size,
                              hipStream_t stream) {
  const int*   code    = (const int*)d_in[0];
  const float* others  = (const float*)d_in[1];
  const int*   length  = (const int*)d_in[2];
  const int*   target  = (const int*)d_in[3];
  const int*   widx    = (const int*)d_in[4];
  const float* Wf      = (const float*)d_in[5];
  const float* bfv     = (const float*)d_in[6];
  const float* Wb      = (const float*)d_in[7];
  const float* bbv     = (const float*)d_in[8];
  const float* W0      = (const float*)d_in[9];
  const float* b0v     = (const float*)d_in[10];
  const float* W1      = (const float*)d_in[11];
  const float* b1v     = (const float*)d_in[12];

  u16*   wsu = (u16*)d_ws;
  float* wsf = (float*)d_ws;
  float* out = (float*)d_out;

  prep_kernel<<<dim3(312), dim3(256), 0, stream>>>(target, widx, Wf, bfv, Wb, bbv, W0, W1, wsu, wsf);
  gemm_kernel<<<dim3(396,3), dim3(256), 0, stream>>>(code, others, length,
      b0v, b1v, wsu, wsf, out);
}

// Round 10
// 126.154 us; speedup vs baseline: 1.0227x; 1.0227x over previous
//
#include <hip/hip_runtime.h>
#include <hip/hip_bf16.h>

typedef unsigned short u16;
typedef __attribute__((ext_vector_type(8))) short short8;
typedef __attribute__((ext_vector_type(4))) float f32x4;

#define TMAX 200
#define TOUT 198
#define PC 40
#define DOTH 57
#define FWD_OFF 0
#define BWD_OFF 3244032
#define FV_OFF  6488064
// ws byte offsets: packed bf16 weights + f32 tgt folds
#define OWF 0
#define OWB 294912
#define OW0 589824
#define OW1 884736
#define OTF 1015808
#define OTB 1081344

__device__ __forceinline__ u16 f2b(float v) {
  __hip_bfloat16 h = __float2bfloat16(v);
  return *(u16*)&h;
}

// Pack weights to MFMA-frag layout + fold per-batch target block.
// Packed K order (mode 0, Wf/Wb): k 0..56 = dense (orig rows 607+k),
// k 57..563 = code one-hots (orig rows k-57), rest 0.
// mode 1 (W0): k 0..47 = dense (orig 507+k), 48..56 = 0, 57..563 = codes.
__global__ __launch_bounds__(256) void prep_kernel(
    const int* __restrict__ target, const int* __restrict__ widx,
    const float* __restrict__ Wf, const float* __restrict__ bfv,
    const float* __restrict__ Wb, const float* __restrict__ bbv,
    const float* __restrict__ W0, const float* __restrict__ W1,
    u16* __restrict__ wsu, float* __restrict__ wsf)
{
  int blk = blockIdx.x, n = threadIdx.x;
  if (blk < 248) {
    const float* src; u16* dst; int kb; int mode;
    if (blk < 72)       { src=Wf; dst=wsu+OWF/2; kb=blk;     mode=0; }
    else if (blk < 144) { src=Wb; dst=wsu+OWB/2; kb=blk-72;  mode=0; }
    else if (blk < 216) { src=W0; dst=wsu+OW0/2; kb=blk-144; mode=1; }
    else                { src=W1; dst=wsu+OW1/2; kb=blk-216; mode=2; }
    u16 pk[8];
    #pragma unroll
    for (int j=0;j<8;j++) {
      int k = kb*8+j;
      int sr;
      if (mode==0)      sr = (k<57)? 607+k : (k<564)? k-57 : -1;
      else if (mode==1) sr = (k<48)? 507+k : (k<57)? -1 : (k<564)? k-57 : -1;
      else              sr = k;
      float v = (sr>=0)? src[sr*256+n] : 0.f;
      pk[j] = f2b(v);
    }
    *(uint4*)(dst + (kb*256+n)*8) = *(uint4*)pk;
  } else {
    int b = blk - 248;
    __shared__ float tval[100]; __shared__ int tg[10];
    if (n<10) tg[n]=target[b*10+n];
    __syncthreads();
    if (n<100){ int w=widx[n]; float v=1.f;
      #pragma unroll
      for(int i=0;i<10;i++) if(tg[i]==w) v=0.f;
      tval[n]=v; }
    __syncthreads();
    float aF=bfv[n], aB=bbv[n];
    for(int k=0;k<100;k++){ float v=tval[k];
      aF=fmaf(v,Wf[(507+k)*256+n],aF); aB=fmaf(v,Wb[(507+k)*256+n],aB); }
    wsf[OTF/4 + b*256+n]=aF; wsf[OTB/4 + b*256+n]=aB;
  }
}

__global__ __launch_bounds__(256) void gemm_kernel(
    const int* __restrict__ code, const float* __restrict__ others,
    const int* __restrict__ length,
    const float* __restrict__ b0, const float* __restrict__ b1,
    const u16* __restrict__ wsu, const float* __restrict__ wsf,
    float* __restrict__ out)
{
  const int tile = blockIdx.x;   // 0..395 (M-tiles of 32)
  const int strm = blockIdx.y;   // 0 fwd, 1 bwd, 2 mlp
  const int tid = threadIdx.x;
  const int wv = tid>>6, lane = tid&63, q = lane>>4, c = lane&15;
  const int colbase = wv*64 + c;

  // full A-panel: 72 k-blocks x 32 rows x 8 = 18432 u16 = 36 KB
  // layout: lA[kb*256 + row*8 + (k&7)]
  __shared__ u16 lA[18432];
  __shared__ float rpart[4][32];
  u16* lH0 = lA;          // GEMM2 aliases (A dead by then; barrier separates)
  u16* lH1 = lA + 2048;

  // ---- code loads (row meta computed inline) ----
  int mys[5];
  #pragma unroll
  for (int it=0; it<5; it++) {
    int idx = tid + it*256;
    int r = idx/40, p = idx - r*40;
    int m = tile*32 + r;
    int b = m/198, t = m - b*198;
    int L = length[b];
    int s;
    if (strm==0) s = t;
    else if (strm==1) s = (t<L)? (L-1-t) : t;
    else s = t+1;
    mys[it] = (57 + code[(b*TMAX + s)*PC + p]) | (r<<16);
  }

  // ---- dense-dim loads into registers ----
  float dv[8];
  if (strm < 2) {
    #pragma unroll
    for (int it=0; it<8; it++) {
      int idx = tid + it*256;
      float v = 0.f;
      if (idx < 32*57) {
        int r = idx/57, j = idx - r*57;
        int m = tile*32 + r;
        int b = m/198, t = m - b*198;
        int L = length[b];
        int col = (j<27)? j : (j<47)? 37+(j-27) : 27+(j-47);
        int sr;
        if (strm==0) sr = t;
        else if (j < 47) sr = (t<L)? (L-1-t) : t;
        else sr = (t==0)? -1 : (((t-1)<L)? (L-t) : (t-1));
        if (sr >= 0) v = others[(b*TMAX + sr)*DOTH + col];
      }
      dv[it] = v;
    }
  } else {
    #pragma unroll
    for (int it=0; it<6; it++) {
      int idx = tid + it*256;
      int r = idx/48, j = idx - r*48;
      int m = tile*32 + r;
      int b = m/198, t = m - b*198;
      int srow, col;
      if (j<20)      { srow=t+1; col=37+j; }
      else if (j<30) { srow=t+1; col=27+(j-20); }
      else if (j<40) { srow=t+2; col=27+(j-30); }
      else           { srow=t+1; col=19+(j-40); }
      dv[it] = others[(b*TMAX + srow)*DOTH + col];
    }
  }

  // ---- zero full A-panel (2304 uint4) ----
  { uint4 z = {0,0,0,0};
    #pragma unroll
    for (int i=0; i<9; i++) ((uint4*)lA)[tid + i*256] = z; }
  __syncthreads();

  // ---- scatter one-hots + dense into unified panel ----
  #pragma unroll
  for (int it=0; it<5; it++) {
    unsigned d = (unsigned)(mys[it] & 0xFFFF);
    lA[(d>>3)*256 + (mys[it]>>16)*8 + (d&7)] = 0x3F80;  // bf16 1.0
  }
  if (strm < 2) {
    #pragma unroll
    for (int it=0; it<8; it++) {
      int idx = tid + it*256;
      if (idx < 32*57) {
        int r = idx/57, j = idx - r*57;
        lA[(j>>3)*256 + r*8 + (j&7)] = f2b(dv[it]);
      }
    }
  } else {
    #pragma unroll
    for (int it=0; it<6; it++) {
      int idx = tid + it*256;
      int r = idx/48, j = idx - r*48;
      lA[(j>>3)*256 + r*8 + (j&7)] = f2b(dv[it]);
    }
  }
  __syncthreads();

  // ---- barrier-free K-loop: 9 kt x (8 B-frag L2 loads + 2 ds_read_b128 + 16 MFMA) ----
  f32x4 acc[2][4];
  #pragma unroll
  for (int mt=0; mt<2; mt++)
    #pragma unroll
    for (int nt=0; nt<4; nt++)
      #pragma unroll
      for (int reg=0; reg<4; reg++) acc[mt][nt][reg] = 0.f;

  const u16* Wpk = wsu + ((strm==0)? OWF/2 : (strm==1)? OWB/2 : OW0/2);
  for (int kt=0; kt<9; kt++) {
    const u16* gB0 = Wpk + ((kt*8 + q    )*256 + colbase)*8;
    const u16* gB1 = Wpk + ((kt*8 + 4 + q)*256 + colbase)*8;
    short8 bf0[4], bf1[4];
    #pragma unroll
    for (int nt=0; nt<4; nt++) bf0[nt] = *(const short8*)(gB0 + nt*16*8);
    #pragma unroll
    for (int nt=0; nt<4; nt++) bf1[nt] = *(const short8*)(gB1 + nt*16*8);
    short8 af0[2], af1[2];
    #pragma unroll
    for (int mt=0; mt<2; mt++) af0[mt] = *(const short8*)&lA[(kt*8 + q    )*256 + (mt*16 + c)*8];
    #pragma unroll
    for (int mt=0; mt<2; mt++) af1[mt] = *(const short8*)&lA[(kt*8 + 4 + q)*256 + (mt*16 + c)*8];
    #pragma unroll
    for (int mt=0; mt<2; mt++)
      #pragma unroll
      for (int nt=0; nt<4; nt++)
        acc[mt][nt] = __builtin_amdgcn_mfma_f32_16x16x32_bf16(af0[mt], bf0[nt], acc[mt][nt], 0,0,0);
    #pragma unroll
    for (int mt=0; mt<2; mt++)
      #pragma unroll
      for (int nt=0; nt<4; nt++)
        acc[mt][nt] = __builtin_amdgcn_mfma_f32_16x16x32_bf16(af1[mt], bf1[nt], acc[mt][nt], 0,0,0);
  }

  if (strm < 2) {
    // ---- epilogue: add folded tgt+bias, store ----
    const float* tg = wsf + ((strm==0)? OTF/4 : OTB/4);
    float* o = out + ((strm==0)? FWD_OFF : BWD_OFF);
    #pragma unroll
    for (int mt=0; mt<2; mt++)
      #pragma unroll
      for (int reg=0; reg<4; reg++) {
        int rl = mt*16 + q*4 + reg;
        int m = tile*32 + rl;
        int b = m/198, t = m - b*198;
        const float* tr = tg + b*256;
        float* orow = o + (b*TOUT + t)*256 + colbase;
        #pragma unroll
        for (int nt=0; nt<4; nt++) orow[nt*16] = acc[mt][nt][reg] + tr[colbase + nt*16];
      }
  } else {
    // ---- GEMM2: h = relu(acc + b0); chunks ping-pong via lH0/lH1 (alias lA) ----
    __syncthreads();   // all K-loop lA reads complete before overwrite
    if (wv == 0) {
      #pragma unroll
      for (int mt=0; mt<2; mt++)
        #pragma unroll
        for (int reg=0; reg<4; reg++) {
          int rl = mt*16 + q*4 + reg;
          #pragma unroll
          for (int nt=0; nt<4; nt++) {
            int kl = c + nt*16;
            lH0[(kl>>3)*256 + rl*8 + (kl&7)] =
                f2b(fmaxf(acc[mt][nt][reg] + b0[colbase + nt*16], 0.f));
          }
        }
    }
    __syncthreads();
    f32x4 a2[2][4];
    #pragma unroll
    for (int nt=0; nt<4; nt++){ float v = b1[colbase + nt*16];
      #pragma unroll
      for (int mt=0; mt<2; mt++)
        #pragma unroll
        for (int reg=0; reg<4; reg++) a2[mt][nt][reg]=v; }
    const u16* W1p = wsu + OW1/2;
    for (int kt2=0; kt2<4; kt2++) {
      if (wv == kt2+1) {   // write next chunk into other buffer
        u16* B2 = ((kt2+1)&1) ? lH1 : lH0;
        #pragma unroll
        for (int mt=0; mt<2; mt++)
          #pragma unroll
          for (int reg=0; reg<4; reg++) {
            int rl = mt*16 + q*4 + reg;
            #pragma unroll
            for (int nt=0; nt<4; nt++) {
              int kl = c + nt*16;
              B2[(kl>>3)*256 + rl*8 + (kl&7)] =
                  f2b(fmaxf(acc[mt][nt][reg] + b0[colbase + nt*16], 0.f));
            }
          }
      }
      const u16* A2 = (kt2&1) ? lH1 : lH0;
      #pragma unroll
      for (int s=0; s<2; s++) {
        int akb = s*4 + q;
        const u16* gB = W1p + ((kt2*8 + akb)*256 + colbase)*8;
        short8 af[2], bf[4];
        #pragma unroll
        for (int nt=0; nt<4; nt++) bf[nt] = *(const short8*)(gB + nt*16*8);
        #pragma unroll
        for (int mt=0; mt<2; mt++) af[mt] = *(const short8*)&A2[akb*256 + (mt*16 + c)*8];
        #pragma unroll
        for (int mt=0; mt<2; mt++)
          #pragma unroll
          for (int nt=0; nt<4; nt++)
            a2[mt][nt] = __builtin_amdgcn_mfma_f32_16x16x32_bf16(af[mt], bf[nt], a2[mt][nt], 0,0,0);
      }
      __syncthreads();
    }
    // row-wise sum of squares -> l2norm + mask
    #pragma unroll
    for (int mt=0; mt<2; mt++)
      #pragma unroll
      for (int reg=0; reg<4; reg++) {
        int rl = mt*16 + q*4 + reg;
        float ss = 0.f;
        #pragma unroll
        for (int nt=0; nt<4; nt++){ float v=a2[mt][nt][reg]; ss = fmaf(v,v,ss); }
        ss += __shfl_xor(ss, 1, 64); ss += __shfl_xor(ss, 2, 64);
        ss += __shfl_xor(ss, 4, 64); ss += __shfl_xor(ss, 8, 64);
        if (c==0) rpart[wv][rl] = ss;
      }
    __syncthreads();
    #pragma unroll
    for (int mt=0; mt<2; mt++)
      #pragma unroll
      for (int reg=0; reg<4; reg++) {
        int rl = mt*16 + q*4 + reg;
        float s = rpart[0][rl]+rpart[1][rl]+rpart[2][rl]+rpart[3][rl];
        float inv = (s>0.f)? (1.0f/sqrtf(s)) : 0.f;
        int m = tile*32 + rl;
        int b = m/198, t = m - b*198;
        if (t >= length[b]-2) inv = 0.f;
        float* orow = out + FV_OFF + (b*TOUT + t)*256 + colbase;
        #pragma unroll
        for (int nt=0; nt<4; nt++) orow[nt*16] = a2[mt][nt][reg]*inv;
      }
  }
}

extern "C" void kernel_launch(void* const* d_in, const int* in_sizes, int n_in,
                              void* d_out, int out_size, void* d_ws, size_t ws_size,
                              hipStream_t stream) {
  const int*   code    = (const int*)d_in[0];
  const float* others  = (const float*)d_in[1];
  const int*   length  = (const int*)d_in[2];
  const int*   target  = (const int*)d_in[3];
  const int*   widx    = (const int*)d_in[4];
  const float* Wf      = (const float*)d_in[5];
  const float* bfv     = (const float*)d_in[6];
  const float* Wb      = (const float*)d_in[7];
  const float* bbv     = (const float*)d_in[8];
  const float* W0      = (const float*)d_in[9];
  const float* b0v     = (const float*)d_in[10];
  const float* W1      = (const float*)d_in[11];
  const float* b1v     = (const float*)d_in[12];

  u16*   wsu = (u16*)d_ws;
  float* wsf = (float*)d_ws;
  float* out = (float*)d_out;

  prep_kernel<<<dim3(312), dim3(256), 0, stream>>>(target, widx, Wf, bfv, Wb, bbv, W0, W1, wsu, wsf);
  gemm_kernel<<<dim3(396,3), dim3(256), 0, stream>>>(code, others, length,
      b0v, b1v, wsu, wsf, out);
}

// Round 11
// 124.927 us; speedup vs baseline: 1.0328x; 1.0098x over previous
//
#include <hip/hip_runtime.h>
#include <hip/hip_bf16.h>

typedef unsigned short u16;
typedef __attribute__((ext_vector_type(8))) short short8;
typedef __attribute__((ext_vector_type(4))) float f32x4;

#define TMAX 200
#define TOUT 198
#define PC 40
#define DOTH 57
#define FWD_OFF 0
#define BWD_OFF 3244032
#define FV_OFF  6488064
// ws byte offsets: packed bf16 weights + f32 tgt folds
#define OWF 0
#define OWB 294912
#define OW0 589824
#define OW1 884736
#define OTF 1015808
#define OTB 1081344

__device__ __forceinline__ u16 f2b(float v) {
  __hip_bfloat16 h = __float2bfloat16(v);
  return *(u16*)&h;
}

// Pack weights to MFMA-frag layout + fold per-batch target block.
// Packed K order (mode 0, Wf/Wb): k 0..56 = dense (orig rows 607+k),
// k 57..563 = code one-hots (orig rows k-57), rest 0.
// mode 1 (W0): k 0..47 = dense (orig 507+k), 48..56 = 0, 57..563 = codes.
__global__ __launch_bounds__(256) void prep_kernel(
    const int* __restrict__ target, const int* __restrict__ widx,
    const float* __restrict__ Wf, const float* __restrict__ bfv,
    const float* __restrict__ Wb, const float* __restrict__ bbv,
    const float* __restrict__ W0, const float* __restrict__ W1,
    u16* __restrict__ wsu, float* __restrict__ wsf)
{
  int blk = blockIdx.x, n = threadIdx.x;
  if (blk < 248) {
    const float* src; u16* dst; int kb; int mode;
    if (blk < 72)       { src=Wf; dst=wsu+OWF/2; kb=blk;     mode=0; }
    else if (blk < 144) { src=Wb; dst=wsu+OWB/2; kb=blk-72;  mode=0; }
    else if (blk < 216) { src=W0; dst=wsu+OW0/2; kb=blk-144; mode=1; }
    else                { src=W1; dst=wsu+OW1/2; kb=blk-216; mode=2; }
    u16 pk[8];
    #pragma unroll
    for (int j=0;j<8;j++) {
      int k = kb*8+j;
      int sr;
      if (mode==0)      sr = (k<57)? 607+k : (k<564)? k-57 : -1;
      else if (mode==1) sr = (k<48)? 507+k : (k<57)? -1 : (k<564)? k-57 : -1;
      else              sr = k;
      float v = (sr>=0)? src[sr*256+n] : 0.f;
      pk[j] = f2b(v);
    }
    *(uint4*)(dst + (kb*256+n)*8) = *(uint4*)pk;
  } else {
    int b = blk - 248;
    __shared__ float tval[100]; __shared__ int tg[10];
    if (n<10) tg[n]=target[b*10+n];
    __syncthreads();
    if (n<100){ int w=widx[n]; float v=1.f;
      #pragma unroll
      for(int i=0;i<10;i++) if(tg[i]==w) v=0.f;
      tval[n]=v; }
    __syncthreads();
    float aF=bfv[n], aB=bbv[n];
    for(int k=0;k<100;k++){ float v=tval[k];
      aF=fmaf(v,Wf[(507+k)*256+n],aF); aB=fmaf(v,Wb[(507+k)*256+n],aB); }
    wsf[OTF/4 + b*256+n]=aF; wsf[OTB/4 + b*256+n]=aB;
  }
}

__global__ __launch_bounds__(256, 4) void gemm_kernel(
    const int* __restrict__ code, const float* __restrict__ others,
    const int* __restrict__ length,
    const float* __restrict__ b0, const float* __restrict__ b1,
    const u16* __restrict__ wsu, const float* __restrict__ wsf,
    float* __restrict__ out)
{
  const int tile = blockIdx.x;   // 0..395 (M-tiles of 32)
  const int strm = blockIdx.y;   // 0 fwd, 1 bwd, 2 mlp
  const int tid = threadIdx.x;
  const int wv = tid>>6, lane = tid&63, q = lane>>4, c = lane&15;
  const int colbase = wv*64 + c;

  // full A-panel: 72 k-blocks x 32 rows x 8 = 18432 u16 = 36 KB
  // layout: lA[kb*256 + row*8 + (k&7)]
  __shared__ u16 lA[18432];
  __shared__ float rpart[4][32];
  u16* lH0 = lA;          // GEMM2 aliases (A dead by then; barrier separates)
  u16* lH1 = lA + 2048;

  // ---- code loads (row meta computed inline) ----
  int mys[5];
  #pragma unroll
  for (int it=0; it<5; it++) {
    int idx = tid + it*256;
    int r = idx/40, p = idx - r*40;
    int m = tile*32 + r;
    int b = m/198, t = m - b*198;
    int L = length[b];
    int s;
    if (strm==0) s = t;
    else if (strm==1) s = (t<L)? (L-1-t) : t;
    else s = t+1;
    mys[it] = (57 + code[(b*TMAX + s)*PC + p]) | (r<<16);
  }

  // ---- dense-dim loads into registers ----
  float dv[8];
  if (strm < 2) {
    #pragma unroll
    for (int it=0; it<8; it++) {
      int idx = tid + it*256;
      float v = 0.f;
      if (idx < 32*57) {
        int r = idx/57, j = idx - r*57;
        int m = tile*32 + r;
        int b = m/198, t = m - b*198;
        int L = length[b];
        int col = (j<27)? j : (j<47)? 37+(j-27) : 27+(j-47);
        int sr;
        if (strm==0) sr = t;
        else if (j < 47) sr = (t<L)? (L-1-t) : t;
        else sr = (t==0)? -1 : (((t-1)<L)? (L-t) : (t-1));
        if (sr >= 0) v = others[(b*TMAX + sr)*DOTH + col];
      }
      dv[it] = v;
    }
  } else {
    #pragma unroll
    for (int it=0; it<6; it++) {
      int idx = tid + it*256;
      int r = idx/48, j = idx - r*48;
      int m = tile*32 + r;
      int b = m/198, t = m - b*198;
      int srow, col;
      if (j<20)      { srow=t+1; col=37+j; }
      else if (j<30) { srow=t+1; col=27+(j-20); }
      else if (j<40) { srow=t+2; col=27+(j-30); }
      else           { srow=t+1; col=19+(j-40); }
      dv[it] = others[(b*TMAX + srow)*DOTH + col];
    }
  }

  // ---- zero full A-panel (2304 uint4) ----
  { uint4 z = {0,0,0,0};
    #pragma unroll
    for (int i=0; i<9; i++) ((uint4*)lA)[tid + i*256] = z; }
  __syncthreads();

  // ---- scatter one-hots + dense into unified panel ----
  #pragma unroll
  for (int it=0; it<5; it++) {
    unsigned d = (unsigned)(mys[it] & 0xFFFF);
    lA[(d>>3)*256 + (mys[it]>>16)*8 + (d&7)] = 0x3F80;  // bf16 1.0
  }
  if (strm < 2) {
    #pragma unroll
    for (int it=0; it<8; it++) {
      int idx = tid + it*256;
      if (idx < 32*57) {
        int r = idx/57, j = idx - r*57;
        lA[(j>>3)*256 + r*8 + (j&7)] = f2b(dv[it]);
      }
    }
  } else {
    #pragma unroll
    for (int it=0; it<6; it++) {
      int idx = tid + it*256;
      int r = idx/48, j = idx - r*48;
      lA[(j>>3)*256 + r*8 + (j&7)] = f2b(dv[it]);
    }
  }
  __syncthreads();

  // ---- barrier-free K-loop with 1-iter-ahead B prefetch (vmcnt never drains) ----
  f32x4 acc[2][4];
  #pragma unroll
  for (int mt=0; mt<2; mt++)
    #pragma unroll
    for (int nt=0; nt<4; nt++)
      #pragma unroll
      for (int reg=0; reg<4; reg++) acc[mt][nt][reg] = 0.f;

  const u16* Wpk = wsu + ((strm==0)? OWF/2 : (strm==1)? OWB/2 : OW0/2);
  short8 nb0[4], nb1[4];
  {
    const u16* g0 = Wpk + ((q    )*256 + colbase)*8;
    const u16* g1 = Wpk + ((4 + q)*256 + colbase)*8;
    #pragma unroll
    for (int nt=0; nt<4; nt++) { nb0[nt] = *(const short8*)(g0 + nt*128);
                                 nb1[nt] = *(const short8*)(g1 + nt*128); }
  }
  #pragma unroll
  for (int kt=0; kt<9; kt++) {
    short8 bf0[4], bf1[4];
    #pragma unroll
    for (int nt=0; nt<4; nt++) { bf0[nt] = nb0[nt]; bf1[nt] = nb1[nt]; }
    if (kt < 8) {   // issue next tile's B loads before consuming this tile
      const u16* g0 = Wpk + (((kt+1)*8 + q    )*256 + colbase)*8;
      const u16* g1 = Wpk + (((kt+1)*8 + 4 + q)*256 + colbase)*8;
      #pragma unroll
      for (int nt=0; nt<4; nt++) { nb0[nt] = *(const short8*)(g0 + nt*128);
                                   nb1[nt] = *(const short8*)(g1 + nt*128); }
    }
    short8 af0[2], af1[2];
    #pragma unroll
    for (int mt=0; mt<2; mt++) af0[mt] = *(const short8*)&lA[(kt*8 + q    )*256 + (mt*16 + c)*8];
    #pragma unroll
    for (int mt=0; mt<2; mt++) af1[mt] = *(const short8*)&lA[(kt*8 + 4 + q)*256 + (mt*16 + c)*8];
    #pragma unroll
    for (int mt=0; mt<2; mt++)
      #pragma unroll
      for (int nt=0; nt<4; nt++)
        acc[mt][nt] = __builtin_amdgcn_mfma_f32_16x16x32_bf16(af0[mt], bf0[nt], acc[mt][nt], 0,0,0);
    #pragma unroll
    for (int mt=0; mt<2; mt++)
      #pragma unroll
      for (int nt=0; nt<4; nt++)
        acc[mt][nt] = __builtin_amdgcn_mfma_f32_16x16x32_bf16(af1[mt], bf1[nt], acc[mt][nt], 0,0,0);
  }

  if (strm < 2) {
    // ---- epilogue: add folded tgt+bias, store ----
    const float* tg = wsf + ((strm==0)? OTF/4 : OTB/4);
    float* o = out + ((strm==0)? FWD_OFF : BWD_OFF);
    #pragma unroll
    for (int mt=0; mt<2; mt++)
      #pragma unroll
      for (int reg=0; reg<4; reg++) {
        int rl = mt*16 + q*4 + reg;
        int m = tile*32 + rl;
        int b = m/198, t = m - b*198;
        const float* tr = tg + b*256;
        float* orow = o + (b*TOUT + t)*256 + colbase;
        #pragma unroll
        for (int nt=0; nt<4; nt++) orow[nt*16] = acc[mt][nt][reg] + tr[colbase + nt*16];
      }
  } else {
    // ---- GEMM2: h = relu(acc + b0); chunks ping-pong via lH0/lH1 (alias lA) ----
    __syncthreads();   // all K-loop lA reads complete before overwrite
    if (wv == 0) {
      #pragma unroll
      for (int mt=0; mt<2; mt++)
        #pragma unroll
        for (int reg=0; reg<4; reg++) {
          int rl = mt*16 + q*4 + reg;
          #pragma unroll
          for (int nt=0; nt<4; nt++) {
            int kl = c + nt*16;
            lH0[(kl>>3)*256 + rl*8 + (kl&7)] =
                f2b(fmaxf(acc[mt][nt][reg] + b0[colbase + nt*16], 0.f));
          }
        }
    }
    __syncthreads();
    f32x4 a2[2][4];
    #pragma unroll
    for (int nt=0; nt<4; nt++){ float v = b1[colbase + nt*16];
      #pragma unroll
      for (int mt=0; mt<2; mt++)
        #pragma unroll
        for (int reg=0; reg<4; reg++) a2[mt][nt][reg]=v; }
    const u16* W1p = wsu + OW1/2;
    for (int kt2=0; kt2<4; kt2++) {
      if (wv == kt2+1) {   // write next chunk into other buffer
        u16* B2 = ((kt2+1)&1) ? lH1 : lH0;
        #pragma unroll
        for (int mt=0; mt<2; mt++)
          #pragma unroll
          for (int reg=0; reg<4; reg++) {
            int rl = mt*16 + q*4 + reg;
            #pragma unroll
            for (int nt=0; nt<4; nt++) {
              int kl = c + nt*16;
              B2[(kl>>3)*256 + rl*8 + (kl&7)] =
                  f2b(fmaxf(acc[mt][nt][reg] + b0[colbase + nt*16], 0.f));
            }
          }
      }
      const u16* A2 = (kt2&1) ? lH1 : lH0;
      #pragma unroll
      for (int s=0; s<2; s++) {
        int akb = s*4 + q;
        const u16* gB = W1p + ((kt2*8 + akb)*256 + colbase)*8;
        short8 af[2], bf[4];
        #pragma unroll
        for (int nt=0; nt<4; nt++) bf[nt] = *(const short8*)(gB + nt*16*8);
        #pragma unroll
        for (int mt=0; mt<2; mt++) af[mt] = *(const short8*)&A2[akb*256 + (mt*16 + c)*8];
        #pragma unroll
        for (int mt=0; mt<2; mt++)
          #pragma unroll
          for (int nt=0; nt<4; nt++)
            a2[mt][nt] = __builtin_amdgcn_mfma_f32_16x16x32_bf16(af[mt], bf[nt], a2[mt][nt], 0,0,0);
      }
      __syncthreads();
    }
    // row-wise sum of squares -> l2norm + mask
    #pragma unroll
    for (int mt=0; mt<2; mt++)
      #pragma unroll
      for (int reg=0; reg<4; reg++) {
        int rl = mt*16 + q*4 + reg;
        float ss = 0.f;
        #pragma unroll
        for (int nt=0; nt<4; nt++){ float v=a2[mt][nt][reg]; ss = fmaf(v,v,ss); }
        ss += __shfl_xor(ss, 1, 64); ss += __shfl_xor(ss, 2, 64);
        ss += __shfl_xor(ss, 4, 64); ss += __shfl_xor(ss, 8, 64);
        if (c==0) rpart[wv][rl] = ss;
      }
    __syncthreads();
    #pragma unroll
    for (int mt=0; mt<2; mt++)
      #pragma unroll
      for (int reg=0; reg<4; reg++) {
        int rl = mt*16 + q*4 + reg;
        float s = rpart[0][rl]+rpart[1][rl]+rpart[2][rl]+rpart[3][rl];
        float inv = (s>0.f)? (1.0f/sqrtf(s)) : 0.f;
        int m = tile*32 + rl;
        int b = m/198, t = m - b*198;
        if (t >= length[b]-2) inv = 0.f;
        float* orow = out + FV_OFF + (b*TOUT + t)*256 + colbase;
        #pragma unroll
        for (int nt=0; nt<4; nt++) orow[nt*16] = a2[mt][nt][reg]*inv;
      }
  }
}

extern "C" void kernel_launch(void* const* d_in, const int* in_sizes, int n_in,
                              void* d_out, int out_size, void* d_ws, size_t ws_size,
                              hipStream_t stream) {
  const int*   code    = (const int*)d_in[0];
  const float* others  = (const float*)d_in[1];
  const int*   length  = (const int*)d_in[2];
  const int*   target  = (const int*)d_in[3];
  const int*   widx    = (const int*)d_in[4];
  const float* Wf      = (const float*)d_in[5];
  const float* bfv     = (const float*)d_in[6];
  const float* Wb      = (const float*)d_in[7];
  const float* bbv     = (const float*)d_in[8];
  const float* W0      = (const float*)d_in[9];
  const float* b0v     = (const float*)d_in[10];
  const float* W1      = (const float*)d_in[11];
  const float* b1v     = (const float*)d_in[12];

  u16*   wsu = (u16*)d_ws;
  float* wsf = (float*)d_ws;
  float* out = (float*)d_out;

  prep_kernel<<<dim3(312), dim3(256), 0, stream>>>(target, widx, Wf, bfv, Wb, bbv, W0, W1, wsu, wsf);
  gemm_kernel<<<dim3(396,3), dim3(256), 0, stream>>>(code, others, length,
      b0v, b1v, wsu, wsf, out);
}